// Round 1
// baseline (305.460 us; speedup 1.0000x reference)
//
#include <hip/hip_runtime.h>

#define N_E   1024
#define EDIM  256
#define BB    16
#define TT    1024
#define NROW  (BB*TT)        /* 16384 */
#define NCOL  1025
#define NPAD  1152           /* 9*128 */
#define PERS  (0.1f/1024.0f)
#define EPSC  (1e-6f/1024.0f)

/* d_out layout (float32): z_q [0,4194304) | loss 4194304 | ind [4194305,+16384) | v 4210689 */
#define OUT_LOSS 4194304
#define OUT_IDX  4194305
#define OUT_V    4210689

/* ws layout (bytes) */
#define WS_ZB   0ull                               /* 16384*256*2  = 8388608  */
#define WS_BBF  8388608ull                         /* 1152*256*2   = 589824   */
#define WS_BSQ  8978432ull                         /* 1152*4       = 4608     */
#define WS_E    8983552ull                         /* 16384*1152*4 = 75497472 */
#define WS_IND  84481024ull                        /* 16384*4                 */
#define WS_PART 84546560ull                        /* 16384*4                 */

typedef __attribute__((ext_vector_type(8))) short short8;
typedef __attribute__((ext_vector_type(4))) float floatx4;

__device__ __forceinline__ unsigned short f2bf(float f) {
    unsigned int u = __float_as_uint(f);
    u = (u + 0x7fffu + ((u >> 16) & 1u)) >> 16;   /* RNE */
    return (unsigned short)u;
}

/* ---------------- K0: convert z/book -> bf16, compute bsq (fp32) ---------------- */
__global__ __launch_bounds__(256) void k0_prep(const float* __restrict__ z,
                                               const float* __restrict__ book,
                                               unsigned short* __restrict__ zb,
                                               unsigned short* __restrict__ bb,
                                               float* __restrict__ bsq) {
    int bx = blockIdx.x, tid = threadIdx.x;
    if (bx < 4096) {                     /* z: 4096 blocks * 256 thr * 4 floats */
        float4 v = ((const float4*)z)[bx * 256 + tid];
        size_t o = ((size_t)bx * 256 + tid) * 4;
        zb[o + 0] = f2bf(v.x); zb[o + 1] = f2bf(v.y);
        zb[o + 2] = f2bf(v.z); zb[o + 3] = f2bf(v.w);
    } else {                             /* book rows, padded to 1152 with zeros */
        int row = bx - 4096;             /* 0..1151 */
        float v = (row < NCOL) ? book[(size_t)row * EDIM + tid] : 0.0f;
        bb[(size_t)row * EDIM + tid] = f2bf(v);
        __shared__ float sd[256];
        sd[tid] = v * v;
        __syncthreads();
        for (int s = 128; s > 0; s >>= 1) { if (tid < s) sd[tid] += sd[tid + s]; __syncthreads(); }
        if (tid == 0) bsq[row] = sd[0];
    }
}

/* ---------------- K1: e[r][n] = bsq[n] - 2 * dot(z[r], book[n])  (bf16 MFMA) ----
   Block 256 thr = 4 waves (2x2), each wave a 64x64 tile via 4x4 of 16x16x32 MFMA.
   A and B fragments both loaded row-major [row][k]: lane reads row (lane&15),
   k0 = (lane>>4)*8; C/D: col(n)=lane&15, row(m)=(lane>>4)*4+reg  (m89/m91).   */
__global__ __launch_bounds__(256) void k1_gemm(const unsigned short* __restrict__ zb,
                                               const unsigned short* __restrict__ bb,
                                               const float* __restrict__ bsq,
                                               float* __restrict__ e) {
    int tid = threadIdx.x;
    int lane = tid & 63, w = tid >> 6;
    int mBase = blockIdx.x * 128 + (w >> 1) * 64;
    int nBase = blockIdx.y * 128 + (w & 1) * 64;
    int r = lane & 15, q = lane >> 4;

    floatx4 acc[4][4];
    #pragma unroll
    for (int i = 0; i < 4; i++)
        #pragma unroll
        for (int j = 0; j < 4; j++) acc[i][j] = (floatx4){0.f, 0.f, 0.f, 0.f};

    const short8* A = (const short8*)zb;   /* row stride 256 bf16 = 32 short8 */
    const short8* Bm = (const short8*)bb;

    #pragma unroll
    for (int ks = 0; ks < 8; ks++) {
        int k8 = ks * 4 + q;               /* short8 index in row: (ks*32+q*8)/8 */
        short8 a[4], b[4];
        #pragma unroll
        for (int i = 0; i < 4; i++) a[i] = A[(size_t)(mBase + i * 16 + r) * 32 + k8];
        #pragma unroll
        for (int j = 0; j < 4; j++) b[j] = Bm[(size_t)(nBase + j * 16 + r) * 32 + k8];
        #pragma unroll
        for (int i = 0; i < 4; i++)
            #pragma unroll
            for (int j = 0; j < 4; j++)
                acc[i][j] = __builtin_amdgcn_mfma_f32_16x16x32_bf16(a[i], b[j], acc[i][j], 0, 0, 0);
    }

    float bsql[4];
    #pragma unroll
    for (int j = 0; j < 4; j++) bsql[j] = bsq[nBase + j * 16 + r];

    #pragma unroll
    for (int i = 0; i < 4; i++)
        #pragma unroll
        for (int rr = 0; rr < 4; rr++) {
            int m = mBase + i * 16 + q * 4 + rr;
            float* erow = e + (size_t)m * NPAD;
            #pragma unroll
            for (int j = 0; j < 4; j++)
                erow[nBase + j * 16 + r] = fmaf(-2.0f, acc[i][j][rr], bsql[j]);
        }
}

/* ---------------- K2: serial neighbor scan, one block per batch row ------------
   Phase A (4 waves): fp32 argmin of d[b,0,:] reference-style (quant at ~256).
   Phase B (wave 0): window=64 cols, chunks of 30 steps, prefetch next chunk
   with base = ind at current chunk start (provably covers next chunk).       */
__global__ __launch_bounds__(256) void k2_scan(const float* __restrict__ z,
                                               const float* __restrict__ book,
                                               const float* __restrict__ bsq,
                                               const float* __restrict__ e,
                                               int* __restrict__ wind,
                                               float* __restrict__ out) {
    int b = blockIdx.x, tid = threadIdx.x;
    int lane = tid & 63, w = tid >> 6;

    const float4* zr = (const float4*)(z + (size_t)b * TT * EDIM);  /* t=0 row */
    float4 zv = zr[lane];
    float s = zv.x * zv.x + zv.y * zv.y + zv.z * zv.z + zv.w * zv.w;
    #pragma unroll
    for (int off = 32; off; off >>= 1) s += __shfl_xor(s, off, 64);
    float zsq = s;

    float best = 3.4e38f; int bidx = 0;
    for (int wi = w; wi < 17; wi += 4) {
        int n = wi * 64 + lane;
        if (n < NCOL) {
            const float4* br = (const float4*)(book + (size_t)n * EDIM);
            float c0 = 0.f, c1 = 0.f, c2 = 0.f, c3 = 0.f;
            #pragma unroll 8
            for (int k = 0; k < 64; k++) {
                float4 bo = br[k]; float4 za = zr[k];
                c0 = fmaf(za.x, bo.x, c0); c1 = fmaf(za.y, bo.y, c1);
                c2 = fmaf(za.z, bo.z, c2); c3 = fmaf(za.w, bo.w, c3);
            }
            float cr = (c0 + c1) + (c2 + c3);
            float d0 = (zsq + bsq[n]) - 2.0f * cr;     /* reference-style formation */
            if (d0 < best || (d0 == best && n < bidx)) { best = d0; bidx = n; }
        }
    }
    #pragma unroll
    for (int off = 32; off; off >>= 1) {
        float ob = __shfl_xor(best, off, 64);
        int   oi = __shfl_xor(bidx, off, 64);
        if (ob < best || (ob == best && oi < bidx)) { best = ob; bidx = oi; }
    }
    __shared__ float sb[4]; __shared__ int si[4];
    if (lane == 0) { sb[w] = best; si[w] = bidx; }
    __syncthreads();
    if (w != 0) return;

    best = sb[0]; bidx = si[0];
    for (int i = 1; i < 4; i++) {
        float vv = sb[i]; int ii = si[i];
        if (vv < best || (vv == best && ii < bidx)) { best = vv; bidx = ii; }
    }

    int ind = min(bidx, N_E - 1);
    float coe = 0.0f;
    size_t ibase = (size_t)b * TT;
    if (lane == 0) { out[OUT_IDX + ibase] = (float)ind; wind[ibase] = ind; }

    const float* eb = e + (size_t)b * TT * NPAD;
    float cur[30], nxt[30];
    int cb_cur = min(ind, 960);
    #pragma unroll
    for (int j = 0; j < 30; j++)
        cur[j] = eb[(size_t)(1 + j) * NPAD + cb_cur + lane];

    int t = 1;
    while (t < 1024) {
        int cb_nxt = min(ind, 960);        /* base for NEXT chunk: ind at current chunk start */
        #pragma unroll
        for (int j = 0; j < 30; j++) {
            int tn = t + 30 + j; tn = tn < 1024 ? tn : 1023;
            nxt[j] = eb[(size_t)tn * NPAD + cb_nxt + lane];
        }
        #pragma unroll
        for (int j = 0; j < 30; j++) {
            if (t + j < 1024) {
                float here = __shfl(cur[j], ind - cb_cur, 64);
                int nc = min(ind + 1, N_E - 1);
                float nv = __shfl(cur[j], nc - cb_cur, 64);
                bool stay = (here <= nv - coe);
                ind = stay ? ind : nc;
                coe = stay ? (coe + PERS) : 0.0f;
                if (lane == 0) { out[OUT_IDX + ibase + t + j] = (float)ind; wind[ibase + t + j] = ind; }
            }
        }
        #pragma unroll
        for (int j = 0; j < 30; j++) cur[j] = nxt[j];
        cb_cur = cb_nxt;
        t += 30;
    }
}

/* ---------------- K3: per-row hinge-loss partial + z_q gather ---------------- */
__global__ __launch_bounds__(256) void k3_loss_zq(const float* __restrict__ e,
                                                  const int* __restrict__ wind,
                                                  const float* __restrict__ book,
                                                  float* __restrict__ part,
                                                  float* __restrict__ out) {
    int rIdx = blockIdx.x, tid = threadIdx.x;
    int ind = wind[rIdx];
    const float* er = e + (size_t)rIdx * NPAD;
    float eind = er[ind];
    float p = 0.0f;
    for (int n = tid; n < NCOL; n += 256) {
        float v = eind - er[n] + EPSC;
        p += v > 0.0f ? v : 0.0f;
    }
    __shared__ float sd[256];
    sd[tid] = p; __syncthreads();
    for (int s = 128; s > 0; s >>= 1) { if (tid < s) sd[tid] += sd[tid + s]; __syncthreads(); }
    if (tid == 0) part[rIdx] = sd[0];
    out[(size_t)rIdx * 256 + tid] = book[(size_t)ind * EDIM + tid];   /* z_q */
}

/* ---------------- K4: final loss reduce + v ---------------- */
__global__ __launch_bounds__(256) void k4_final(const float* __restrict__ part,
                                                const int* __restrict__ wind,
                                                float* __restrict__ out) {
    int tid = threadIdx.x;
    float s = 0.0f;
    for (int i = tid; i < NROW; i += 256) s += part[i];
    __shared__ float sd[256];
    sd[tid] = s; __syncthreads();
    for (int st = 128; st > 0; st >>= 1) { if (tid < st) sd[tid] += sd[tid + st]; __syncthreads(); }
    if (tid == 0) {
        int mn = wind[0], mx = wind[TT - 1];
        for (int b = 1; b < BB; b++) {
            mn = min(mn, wind[(size_t)b * TT]);
            mx = max(mx, wind[(size_t)b * TT + TT - 1]);
        }
        out[OUT_LOSS] = 1.25f * sd[0] / ((float)NROW * (float)NCOL);
        out[OUT_V] = (float)(mx - mn);
    }
}

extern "C" void kernel_launch(void* const* d_in, const int* in_sizes, int n_in,
                              void* d_out, int out_size, void* d_ws, size_t ws_size,
                              hipStream_t stream) {
    const float* z    = (const float*)d_in[0];
    const float* book = (const float*)d_in[1];
    char* ws = (char*)d_ws;
    unsigned short* zb = (unsigned short*)(ws + WS_ZB);
    unsigned short* bb = (unsigned short*)(ws + WS_BBF);
    float* bsq  = (float*)(ws + WS_BSQ);
    float* e    = (float*)(ws + WS_E);
    int*   wind = (int*)(ws + WS_IND);
    float* part = (float*)(ws + WS_PART);
    float* out  = (float*)d_out;

    hipLaunchKernelGGL(k0_prep,    dim3(4096 + 1152), dim3(256), 0, stream, z, book, zb, bb, bsq);
    hipLaunchKernelGGL(k1_gemm,    dim3(128, 9),      dim3(256), 0, stream, zb, bb, bsq, e);
    hipLaunchKernelGGL(k2_scan,    dim3(16),          dim3(256), 0, stream, z, book, bsq, e, wind, out);
    hipLaunchKernelGGL(k3_loss_zq, dim3(16384),       dim3(256), 0, stream, e, wind, book, part, out);
    hipLaunchKernelGGL(k4_final,   dim3(1),           dim3(256), 0, stream, part, wind, out);
}

// Round 3
// 262.954 us; speedup vs baseline: 1.1616x; 1.1616x over previous
//
#include <hip/hip_runtime.h>

#define N_E   1024
#define EDIM  256
#define BB    16
#define TT    1024
#define NROW  (BB*TT)        /* 16384 */
#define NCOL  1025
#define NPAD  1152           /* 9*128 */
#define PERS  (0.1f/1024.0f)
#define EPSC  (1e-6f/1024.0f)

/* d_out layout (float32): z_q [0,4194304) | loss 4194304 | ind [4194305,+16384) | v 4210689 */
#define OUT_LOSS 4194304
#define OUT_IDX  4194305
#define OUT_V    4210689

/* ws layout (bytes) */
#define WS_ZB   0ull                               /* 16384*256*2  = 8388608  */
#define WS_BBF  8388608ull                         /* 1152*256*2   = 589824   */
#define WS_BSQ  8978432ull                         /* 1152*4       = 4608     */
#define WS_E    8983552ull                         /* 16384*1152*4 = 75497472 */
#define WS_IND  84481024ull                        /* 16384*4                 */
#define WS_PART 84546560ull                        /* 16384*4                 */

typedef __attribute__((ext_vector_type(8))) short short8;
typedef __attribute__((ext_vector_type(4))) float floatx4;

__device__ __forceinline__ unsigned short f2bf(float f) {
    unsigned int u = __float_as_uint(f);
    u = (u + 0x7fffu + ((u >> 16) & 1u)) >> 16;   /* RNE */
    return (unsigned short)u;
}

/* ---------------- K0: convert z/book -> bf16, compute bsq (fp32) ---------------- */
__global__ __launch_bounds__(256) void k0_prep(const float* __restrict__ z,
                                               const float* __restrict__ book,
                                               unsigned short* __restrict__ zb,
                                               unsigned short* __restrict__ bb,
                                               float* __restrict__ bsq) {
    int bx = blockIdx.x, tid = threadIdx.x;
    if (bx < 4096) {                     /* z: 4096 blocks * 256 thr * 4 floats */
        float4 v = ((const float4*)z)[bx * 256 + tid];
        size_t o = ((size_t)bx * 256 + tid) * 4;
        zb[o + 0] = f2bf(v.x); zb[o + 1] = f2bf(v.y);
        zb[o + 2] = f2bf(v.z); zb[o + 3] = f2bf(v.w);
    } else {                             /* book rows, padded to 1152 with zeros */
        int row = bx - 4096;             /* 0..1151 */
        float v = (row < NCOL) ? book[(size_t)row * EDIM + tid] : 0.0f;
        bb[(size_t)row * EDIM + tid] = f2bf(v);
        __shared__ float sd[256];
        sd[tid] = v * v;
        __syncthreads();
        for (int s = 128; s > 0; s >>= 1) { if (tid < s) sd[tid] += sd[tid + s]; __syncthreads(); }
        if (tid == 0) bsq[row] = sd[0];
    }
}

/* ---------------- K1: e[r][n] = bsq[n] - 2 * dot(z[r], book[n])  (bf16 MFMA) ----
   Block 256 thr = 4 waves (2x2), each wave a 64x64 tile via 4x4 of 16x16x32 MFMA.
   A and B fragments both loaded row-major [row][k]: lane reads row (lane&15),
   k0 = (lane>>4)*8; C/D: col(n)=lane&15, row(m)=(lane>>4)*4+reg  (m89/m91).   */
__global__ __launch_bounds__(256) void k1_gemm(const unsigned short* __restrict__ zb,
                                               const unsigned short* __restrict__ bb,
                                               const float* __restrict__ bsq,
                                               float* __restrict__ e) {
    int tid = threadIdx.x;
    int lane = tid & 63, w = tid >> 6;
    int mBase = blockIdx.x * 128 + (w >> 1) * 64;
    int nBase = blockIdx.y * 128 + (w & 1) * 64;
    int r = lane & 15, q = lane >> 4;

    floatx4 acc[4][4];
    #pragma unroll
    for (int i = 0; i < 4; i++)
        #pragma unroll
        for (int j = 0; j < 4; j++) acc[i][j] = (floatx4){0.f, 0.f, 0.f, 0.f};

    const short8* A = (const short8*)zb;   /* row stride 256 bf16 = 32 short8 */
    const short8* Bm = (const short8*)bb;

    #pragma unroll
    for (int ks = 0; ks < 8; ks++) {
        int k8 = ks * 4 + q;               /* short8 index in row: (ks*32+q*8)/8 */
        short8 a[4], b[4];
        #pragma unroll
        for (int i = 0; i < 4; i++) a[i] = A[(size_t)(mBase + i * 16 + r) * 32 + k8];
        #pragma unroll
        for (int j = 0; j < 4; j++) b[j] = Bm[(size_t)(nBase + j * 16 + r) * 32 + k8];
        #pragma unroll
        for (int i = 0; i < 4; i++)
            #pragma unroll
            for (int j = 0; j < 4; j++)
                acc[i][j] = __builtin_amdgcn_mfma_f32_16x16x32_bf16(a[i], b[j], acc[i][j], 0, 0, 0);
    }

    float bsql[4];
    #pragma unroll
    for (int j = 0; j < 4; j++) bsql[j] = bsq[nBase + j * 16 + r];

    #pragma unroll
    for (int i = 0; i < 4; i++)
        #pragma unroll
        for (int rr = 0; rr < 4; rr++) {
            int m = mBase + i * 16 + q * 4 + rr;
            float* erow = e + (size_t)m * NPAD;
            #pragma unroll
            for (int j = 0; j < 4; j++)
                erow[nBase + j * 16 + r] = fmaf(-2.0f, acc[i][j][rr], bsql[j]);
        }
}

/* ---------------- K2: serial neighbor scan, one block per batch row ------------
   Phase A (4 waves): fp32 argmin of d[b,0,:] reference-style.
   Phase B (wave 0): window=64 cols, chunks of 30 steps. Scan state (ind, coe)
   is wave-uniform -> broadcast via v_readlane (VALU latency), NOT ds_bpermute.
   Chunk indices packed via per-lane predicated select; one store per chunk.  */
__global__ __launch_bounds__(256) void k2_scan(const float* __restrict__ z,
                                               const float* __restrict__ book,
                                               const float* __restrict__ bsq,
                                               const float* __restrict__ e,
                                               int* __restrict__ wind) {
    int b = blockIdx.x, tid = threadIdx.x;
    int lane = tid & 63, w = tid >> 6;

    const float4* zr = (const float4*)(z + (size_t)b * TT * EDIM);  /* t=0 row */
    float4 zv = zr[lane];
    float s = zv.x * zv.x + zv.y * zv.y + zv.z * zv.z + zv.w * zv.w;
    #pragma unroll
    for (int off = 32; off; off >>= 1) s += __shfl_xor(s, off, 64);
    float zsq = s;

    float best = 3.4e38f; int bidx = 0;
    for (int wi = w; wi < 17; wi += 4) {
        int n = wi * 64 + lane;
        if (n < NCOL) {
            const float4* br = (const float4*)(book + (size_t)n * EDIM);
            float c0 = 0.f, c1 = 0.f, c2 = 0.f, c3 = 0.f;
            #pragma unroll 8
            for (int k = 0; k < 64; k++) {
                float4 bo = br[k]; float4 za = zr[k];
                c0 = fmaf(za.x, bo.x, c0); c1 = fmaf(za.y, bo.y, c1);
                c2 = fmaf(za.z, bo.z, c2); c3 = fmaf(za.w, bo.w, c3);
            }
            float cr = (c0 + c1) + (c2 + c3);
            float d0 = (zsq + bsq[n]) - 2.0f * cr;     /* reference-style formation */
            if (d0 < best || (d0 == best && n < bidx)) { best = d0; bidx = n; }
        }
    }
    #pragma unroll
    for (int off = 32; off; off >>= 1) {
        float ob = __shfl_xor(best, off, 64);
        int   oi = __shfl_xor(bidx, off, 64);
        if (ob < best || (ob == best && oi < bidx)) { best = ob; bidx = oi; }
    }
    __shared__ float sb[4]; __shared__ int si[4];
    if (lane == 0) { sb[w] = best; si[w] = bidx; }
    __syncthreads();
    if (w != 0) return;

    best = sb[0]; bidx = si[0];
    for (int i = 1; i < 4; i++) {
        float vv = sb[i]; int ii = si[i];
        if (vv < best || (vv == best && ii < bidx)) { best = vv; bidx = ii; }
    }

    int ind = min(bidx, N_E - 1);
    float coe = 0.0f;
    size_t ibase = (size_t)b * TT;
    if (lane == 0) wind[ibase] = ind;

    const float* eb = e + (size_t)b * TT * NPAD;
    float cur[30], nxt[30];
    int cb_cur = min(ind, 960);
    #pragma unroll
    for (int j = 0; j < 30; j++)
        cur[j] = eb[(size_t)(1 + j) * NPAD + cb_cur + lane];

    int t = 1;
    while (t < 1024) {
        int cb_nxt = min(ind, 960);        /* base for NEXT chunk: ind at current chunk start */
        #pragma unroll
        for (int j = 0; j < 30; j++) {
            int tn = t + 30 + j; tn = tn < 1024 ? tn : 1023;
            nxt[j] = eb[(size_t)tn * NPAD + cb_nxt + lane];
        }
        int packed = 0;
        #pragma unroll
        for (int j = 0; j < 30; j++) {
            if (t + j < 1024) {
                /* ind is wave-uniform: readlane (VALU) instead of bpermute (LDS) */
                float here = __uint_as_float(__builtin_amdgcn_readlane(
                                 __float_as_uint(cur[j]), ind - cb_cur));
                int nc = min(ind + 1, N_E - 1);
                float nv = __uint_as_float(__builtin_amdgcn_readlane(
                                 __float_as_uint(cur[j]), nc - cb_cur));
                bool stay = (here <= nv - coe);
                ind = stay ? ind : nc;
                coe = stay ? (coe + PERS) : 0.0f;
                /* pack off the chain: lane j keeps this step's ind */
                packed = (lane == j) ? ind : packed;
            }
        }
        if (lane < 30 && (t + lane) < 1024) wind[ibase + t + lane] = packed;
        #pragma unroll
        for (int j = 0; j < 30; j++) cur[j] = nxt[j];
        cb_cur = cb_nxt;
        t += 30;
    }
}

/* ---------------- K3: per-row hinge-loss partial + z_q gather + idx emit ------ */
__global__ __launch_bounds__(256) void k3_loss_zq(const float* __restrict__ e,
                                                  const int* __restrict__ wind,
                                                  const float* __restrict__ book,
                                                  float* __restrict__ part,
                                                  float* __restrict__ out) {
    int rIdx = blockIdx.x, tid = threadIdx.x;
    int ind = wind[rIdx];
    const float* er = e + (size_t)rIdx * NPAD;
    float eind = er[ind];
    float p = 0.0f;
    for (int n = tid; n < NCOL; n += 256) {
        float v = eind - er[n] + EPSC;
        p += v > 0.0f ? v : 0.0f;
    }
    __shared__ float sd[256];
    sd[tid] = p; __syncthreads();
    for (int s = 128; s > 0; s >>= 1) { if (tid < s) sd[tid] += sd[tid + s]; __syncthreads(); }
    if (tid == 0) { part[rIdx] = sd[0]; out[OUT_IDX + rIdx] = (float)ind; }
    out[(size_t)rIdx * 256 + tid] = book[(size_t)ind * EDIM + tid];   /* z_q */
}

/* ---------------- K4: final loss reduce + v ---------------- */
__global__ __launch_bounds__(256) void k4_final(const float* __restrict__ part,
                                                const int* __restrict__ wind,
                                                float* __restrict__ out) {
    int tid = threadIdx.x;
    float s = 0.0f;
    for (int i = tid; i < NROW; i += 256) s += part[i];
    __shared__ float sd[256];
    sd[tid] = s; __syncthreads();
    for (int st = 128; st > 0; st >>= 1) { if (tid < st) sd[tid] += sd[tid + st]; __syncthreads(); }
    if (tid == 0) {
        int mn = wind[0], mx = wind[TT - 1];
        for (int b = 1; b < BB; b++) {
            mn = min(mn, wind[(size_t)b * TT]);
            mx = max(mx, wind[(size_t)b * TT + TT - 1]);
        }
        out[OUT_LOSS] = 1.25f * sd[0] / ((float)NROW * (float)NCOL);
        out[OUT_V] = (float)(mx - mn);
    }
}

extern "C" void kernel_launch(void* const* d_in, const int* in_sizes, int n_in,
                              void* d_out, int out_size, void* d_ws, size_t ws_size,
                              hipStream_t stream) {
    const float* z    = (const float*)d_in[0];
    const float* book = (const float*)d_in[1];
    char* ws = (char*)d_ws;
    unsigned short* zb = (unsigned short*)(ws + WS_ZB);
    unsigned short* bb = (unsigned short*)(ws + WS_BBF);
    float* bsq  = (float*)(ws + WS_BSQ);
    float* e    = (float*)(ws + WS_E);
    int*   wind = (int*)(ws + WS_IND);
    float* part = (float*)(ws + WS_PART);
    float* out  = (float*)d_out;

    hipLaunchKernelGGL(k0_prep,    dim3(4096 + 1152), dim3(256), 0, stream, z, book, zb, bb, bsq);
    hipLaunchKernelGGL(k1_gemm,    dim3(128, 9),      dim3(256), 0, stream, zb, bb, bsq, e);
    hipLaunchKernelGGL(k2_scan,    dim3(16),          dim3(256), 0, stream, z, book, bsq, e, wind);
    hipLaunchKernelGGL(k3_loss_zq, dim3(16384),       dim3(256), 0, stream, e, wind, book, part, out);
    hipLaunchKernelGGL(k4_final,   dim3(1),           dim3(256), 0, stream, part, wind, out);
}

// Round 4
// 260.264 us; speedup vs baseline: 1.1737x; 1.0103x over previous
//
#include <hip/hip_runtime.h>

#define N_E   1024
#define EDIM  256
#define BB    16
#define TT    1024
#define NROW  (BB*TT)        /* 16384 */
#define NCOL  1025
#define NPAD  1152           /* 9*128 */
#define PERS  (0.1f/1024.0f)
#define EPSC  (1e-6f/1024.0f)

/* d_out layout (float32): z_q [0,4194304) | loss 4194304 | ind [4194305,+16384) | v 4210689 */
#define OUT_LOSS 4194304
#define OUT_IDX  4194305
#define OUT_V    4210689

/* ws layout (bytes) */
#define WS_ZB   0ull                               /* 16384*256*2  = 8388608  */
#define WS_BBF  8388608ull                         /* 1152*256*2   = 589824   */
#define WS_BSQ  8978432ull                         /* 1152*4       = 4608     */
#define WS_E    8983552ull                         /* 16384*1152*4 = 75497472 */
#define WS_IND  84481024ull                        /* 16384*4                 */
#define WS_PART 84546560ull                        /* 16384*4                 */

typedef __attribute__((ext_vector_type(8))) short short8;
typedef __attribute__((ext_vector_type(4))) float floatx4;

__device__ __forceinline__ unsigned short f2bf(float f) {
    unsigned int u = __float_as_uint(f);
    u = (u + 0x7fffu + ((u >> 16) & 1u)) >> 16;   /* RNE */
    return (unsigned short)u;
}

/* ---------------- K0: convert z/book -> bf16, compute bsq (fp32) ---------------- */
__global__ __launch_bounds__(256) void k0_prep(const float* __restrict__ z,
                                               const float* __restrict__ book,
                                               unsigned short* __restrict__ zb,
                                               unsigned short* __restrict__ bb,
                                               float* __restrict__ bsq) {
    int bx = blockIdx.x, tid = threadIdx.x;
    if (bx < 4096) {                     /* z: 4096 blocks * 256 thr * 4 floats */
        float4 v = ((const float4*)z)[bx * 256 + tid];
        size_t o = ((size_t)bx * 256 + tid) * 4;
        zb[o + 0] = f2bf(v.x); zb[o + 1] = f2bf(v.y);
        zb[o + 2] = f2bf(v.z); zb[o + 3] = f2bf(v.w);
    } else {                             /* book rows, padded to 1152 with zeros */
        int row = bx - 4096;             /* 0..1151 */
        float v = (row < NCOL) ? book[(size_t)row * EDIM + tid] : 0.0f;
        bb[(size_t)row * EDIM + tid] = f2bf(v);
        __shared__ float sd[256];
        sd[tid] = v * v;
        __syncthreads();
        for (int s = 128; s > 0; s >>= 1) { if (tid < s) sd[tid] += sd[tid + s]; __syncthreads(); }
        if (tid == 0) bsq[row] = sd[0];
    }
}

/* ---------------- K1: e[r][n] = bsq[n] - 2 * dot(z[r], book[n])  (bf16 MFMA) ---- */
__global__ __launch_bounds__(256) void k1_gemm(const unsigned short* __restrict__ zb,
                                               const unsigned short* __restrict__ bb,
                                               const float* __restrict__ bsq,
                                               float* __restrict__ e) {
    int tid = threadIdx.x;
    int lane = tid & 63, w = tid >> 6;
    int mBase = blockIdx.x * 128 + (w >> 1) * 64;
    int nBase = blockIdx.y * 128 + (w & 1) * 64;
    int r = lane & 15, q = lane >> 4;

    floatx4 acc[4][4];
    #pragma unroll
    for (int i = 0; i < 4; i++)
        #pragma unroll
        for (int j = 0; j < 4; j++) acc[i][j] = (floatx4){0.f, 0.f, 0.f, 0.f};

    const short8* A = (const short8*)zb;   /* row stride 256 bf16 = 32 short8 */
    const short8* Bm = (const short8*)bb;

    #pragma unroll
    for (int ks = 0; ks < 8; ks++) {
        int k8 = ks * 4 + q;               /* short8 index in row: (ks*32+q*8)/8 */
        short8 a[4], b[4];
        #pragma unroll
        for (int i = 0; i < 4; i++) a[i] = A[(size_t)(mBase + i * 16 + r) * 32 + k8];
        #pragma unroll
        for (int j = 0; j < 4; j++) b[j] = Bm[(size_t)(nBase + j * 16 + r) * 32 + k8];
        #pragma unroll
        for (int i = 0; i < 4; i++)
            #pragma unroll
            for (int j = 0; j < 4; j++)
                acc[i][j] = __builtin_amdgcn_mfma_f32_16x16x32_bf16(a[i], b[j], acc[i][j], 0, 0, 0);
    }

    float bsql[4];
    #pragma unroll
    for (int j = 0; j < 4; j++) bsql[j] = bsq[nBase + j * 16 + r];

    #pragma unroll
    for (int i = 0; i < 4; i++)
        #pragma unroll
        for (int rr = 0; rr < 4; rr++) {
            int m = mBase + i * 16 + q * 4 + rr;
            float* erow = e + (size_t)m * NPAD;
            #pragma unroll
            for (int j = 0; j < 4; j++)
                erow[nBase + j * 16 + r] = fmaf(-2.0f, acc[i][j][rr], bsql[j]);
        }
}

/* ---------------- K2: serial neighbor scan, one block per batch row ------------
   Phase A (4 waves): fp32 argmin of d[b,0,:] reference-style.
   Phase B (wave 0): integer-scan formulation. stay <=> coe <= m, coe = k*P,
   q = trunc(m/P) precomputed per (t, col) vectorized -> per-step chain is
   s_sub + v_readlane + s_cmp_le + s_cselect x2 (one readlane, SALU ints).
   m via dual global loads (col, col+1); col 1024 exists in NPAD padding.     */
__global__ __launch_bounds__(256, 1) void k2_scan(const float* __restrict__ z,
                                                  const float* __restrict__ book,
                                                  const float* __restrict__ bsq,
                                                  const float* __restrict__ e,
                                                  int* __restrict__ wind) {
    int b = blockIdx.x, tid = threadIdx.x;
    int lane = tid & 63, w = tid >> 6;

    const float4* zr = (const float4*)(z + (size_t)b * TT * EDIM);  /* t=0 row */
    float4 zv = zr[lane];
    float s = zv.x * zv.x + zv.y * zv.y + zv.z * zv.z + zv.w * zv.w;
    #pragma unroll
    for (int off = 32; off; off >>= 1) s += __shfl_xor(s, off, 64);
    float zsq = s;

    float best = 3.4e38f; int bidx = 0;
    for (int wi = w; wi < 17; wi += 4) {
        int n = wi * 64 + lane;
        if (n < NCOL) {
            const float4* br = (const float4*)(book + (size_t)n * EDIM);
            float c0 = 0.f, c1 = 0.f, c2 = 0.f, c3 = 0.f;
            #pragma unroll 8
            for (int k = 0; k < 64; k++) {
                float4 bo = br[k]; float4 za = zr[k];
                c0 = fmaf(za.x, bo.x, c0); c1 = fmaf(za.y, bo.y, c1);
                c2 = fmaf(za.z, bo.z, c2); c3 = fmaf(za.w, bo.w, c3);
            }
            float cr = (c0 + c1) + (c2 + c3);
            float d0 = (zsq + bsq[n]) - 2.0f * cr;     /* reference-style formation */
            if (d0 < best || (d0 == best && n < bidx)) { best = d0; bidx = n; }
        }
    }
    #pragma unroll
    for (int off = 32; off; off >>= 1) {
        float ob = __shfl_xor(best, off, 64);
        int   oi = __shfl_xor(bidx, off, 64);
        if (ob < best || (ob == best && oi < bidx)) { best = ob; bidx = oi; }
    }
    __shared__ float sb[4]; __shared__ int si[4];
    if (lane == 0) { sb[w] = best; si[w] = bidx; }
    __syncthreads();
    if (w != 0) return;

    best = sb[0]; bidx = si[0];
    for (int i = 1; i < 4; i++) {
        float vv = sb[i]; int ii = si[i];
        if (vv < best || (vv == best && ii < bidx)) { best = vv; bidx = ii; }
    }

    int ind = min(bidx, N_E - 1);
    int kk = 0;                              /* coe = kk * PERS */
    size_t ibase = (size_t)b * TT;
    if (lane == 0) wind[ibase] = ind;

    const float* eb = e + (size_t)b * TT * NPAD;
    const float QS = 1.0f / PERS;            /* 10240 */

    float Av[31], Bv[31];
    int   q[31];

    int cb = min(ind, 960);
    {
        #pragma unroll
        for (int j = 0; j < 31; j++) {
            const float* p = eb + (size_t)(1 + j) * NPAD + cb + lane;
            Av[j] = p[0]; Bv[j] = p[1];
        }
        bool cap = (cb + lane == 1023);
        #pragma unroll
        for (int j = 0; j < 31; j++) {
            int qv = (int)((Bv[j] - Av[j]) * QS);
            q[j] = cap ? 0 : qv;
        }
    }

    int t = 1;
    for (int c = 0; c < 33; c++) {
        int cbn = min(ind, 960);             /* base for chunk c+1 (<= +31 drift/chunk) */
        if (c < 32) {
            #pragma unroll
            for (int j = 0; j < 31; j++) {
                int tn = t + 31 + j; tn = tn < 1024 ? tn : 1023;
                const float* p = eb + (size_t)tn * NPAD + cbn + lane;
                Av[j] = p[0]; Bv[j] = p[1];
            }
        }
        int packed = 0;
        #pragma unroll
        for (int j = 0; j < 31; j++) {
            int rel = ind - cb;
            int qv = __builtin_amdgcn_readlane(q[j], rel);
            bool stay = (kk <= qv);
            int ip1 = ind + 1; ip1 = ip1 < 1023 ? ip1 : 1023;
            ind = stay ? ind : ip1;
            kk  = stay ? kk + 1 : 0;
            packed = (lane == j) ? ind : packed;
        }
        if (lane < 31) wind[ibase + t + lane] = packed;
        if (c < 32) {
            bool cap = (cbn + lane == 1023);
            #pragma unroll
            for (int j = 0; j < 31; j++) {
                int qv = (int)((Bv[j] - Av[j]) * QS);
                q[j] = cap ? 0 : qv;
            }
        }
        cb = cbn;
        t += 31;
    }
}

/* ---------------- K3: per-row hinge-loss partial + z_q gather + idx emit ------ */
__global__ __launch_bounds__(256) void k3_loss_zq(const float* __restrict__ e,
                                                  const int* __restrict__ wind,
                                                  const float* __restrict__ book,
                                                  float* __restrict__ part,
                                                  float* __restrict__ out) {
    int rIdx = blockIdx.x, tid = threadIdx.x;
    int ind = wind[rIdx];
    const float* er = e + (size_t)rIdx * NPAD;
    float eind = er[ind];
    float p = 0.0f;
    for (int n = tid; n < NCOL; n += 256) {
        float v = eind - er[n] + EPSC;
        p += v > 0.0f ? v : 0.0f;
    }
    __shared__ float sd[256];
    sd[tid] = p; __syncthreads();
    for (int s = 128; s > 0; s >>= 1) { if (tid < s) sd[tid] += sd[tid + s]; __syncthreads(); }
    if (tid == 0) { part[rIdx] = sd[0]; out[OUT_IDX + rIdx] = (float)ind; }
    out[(size_t)rIdx * 256 + tid] = book[(size_t)ind * EDIM + tid];   /* z_q */
}

/* ---------------- K4: final loss reduce + v ---------------- */
__global__ __launch_bounds__(256) void k4_final(const float* __restrict__ part,
                                                const int* __restrict__ wind,
                                                float* __restrict__ out) {
    int tid = threadIdx.x;
    float s = 0.0f;
    for (int i = tid; i < NROW; i += 256) s += part[i];
    __shared__ float sd[256];
    sd[tid] = s; __syncthreads();
    for (int st = 128; st > 0; st >>= 1) { if (tid < st) sd[tid] += sd[tid + st]; __syncthreads(); }
    if (tid == 0) {
        int mn = wind[0], mx = wind[TT - 1];
        for (int b = 1; b < BB; b++) {
            mn = min(mn, wind[(size_t)b * TT]);
            mx = max(mx, wind[(size_t)b * TT + TT - 1]);
        }
        out[OUT_LOSS] = 1.25f * sd[0] / ((float)NROW * (float)NCOL);
        out[OUT_V] = (float)(mx - mn);
    }
}

extern "C" void kernel_launch(void* const* d_in, const int* in_sizes, int n_in,
                              void* d_out, int out_size, void* d_ws, size_t ws_size,
                              hipStream_t stream) {
    const float* z    = (const float*)d_in[0];
    const float* book = (const float*)d_in[1];
    char* ws = (char*)d_ws;
    unsigned short* zb = (unsigned short*)(ws + WS_ZB);
    unsigned short* bb = (unsigned short*)(ws + WS_BBF);
    float* bsq  = (float*)(ws + WS_BSQ);
    float* e    = (float*)(ws + WS_E);
    int*   wind = (int*)(ws + WS_IND);
    float* part = (float*)(ws + WS_PART);
    float* out  = (float*)d_out;

    hipLaunchKernelGGL(k0_prep,    dim3(4096 + 1152), dim3(256), 0, stream, z, book, zb, bb, bsq);
    hipLaunchKernelGGL(k1_gemm,    dim3(128, 9),      dim3(256), 0, stream, zb, bb, bsq, e);
    hipLaunchKernelGGL(k2_scan,    dim3(16),          dim3(256), 0, stream, z, book, bsq, e, wind);
    hipLaunchKernelGGL(k3_loss_zq, dim3(16384),       dim3(256), 0, stream, e, wind, book, part, out);
    hipLaunchKernelGGL(k4_final,   dim3(1),           dim3(256), 0, stream, part, wind, out);
}